// Round 6
// baseline (417.976 us; speedup 1.0000x reference)
//
#include <hip/hip_runtime.h>
#include <hip/hip_bf16.h>
#include <math.h>

using bf16 = __hip_bfloat16;
typedef short bf16x8 __attribute__((ext_vector_type(8)));
typedef float f32x4 __attribute__((ext_vector_type(4)));

#define GAMMA_LOG2 (-0.0014434688536725045f)  // log2(0.999)

union Bf16Bits { bf16 h; unsigned short s; };

__device__ inline unsigned short bf16_bits(float z)
{
    Bf16Bits u;
    u.h = __float2bfloat16(z);
    return u.s;
}

__device__ inline unsigned int packbf2(float a, float b)
{
    return (unsigned int)bf16_bits(a) | ((unsigned int)bf16_bits(b) << 16);
}

// ---------- merged weight prep: 7 fp32 (R x C) -> bf16 (C x R) transposes in one launch ----------
struct PrepArgs {
    const float* src[7];
    bf16* dst[7];
    int R[7];
    int C[7];
    int pfx[8];  // tile prefix sums
};

__global__ void k_prep(PrepArgs pa)
{
    __shared__ float tile[32][33];
    int bid = blockIdx.x;
    int seg = 0;
    while (bid >= pa.pfx[seg + 1]) ++seg;
    int local = bid - pa.pfx[seg];
    int R = pa.R[seg], C = pa.C[seg];
    int ctiles = C >> 5;
    int c0 = (local % ctiles) * 32, r0 = (local / ctiles) * 32;
    const float* in = pa.src[seg];
    bf16* out = pa.dst[seg];
    int tx = threadIdx.x & 31, ty = threadIdx.x >> 5;
#pragma unroll
    for (int i = 0; i < 4; ++i) {
        int r = r0 + ty + 8 * i;
        tile[ty + 8 * i][tx] = in[(size_t)r * C + c0 + tx];
    }
    __syncthreads();
#pragma unroll
    for (int i = 0; i < 4; ++i) {
        int cc = c0 + ty + 8 * i, rr = r0 + tx;
        out[(size_t)cc * R + rr] = __float2bfloat16(tile[tx][ty + 8 * i]);
    }
}

// ---------- bf16 transpose: in (R x C slice at col0, row stride in_stride) -> out (C x R); batched via z ----------
__global__ void k_transpose_bf16(const bf16* __restrict__ in, bf16* __restrict__ out,
                                 int R, int C, int in_stride, int in_col0,
                                 size_t in_bstride, size_t out_bstride)
{
    __shared__ unsigned short tile[32][33];
    in += (size_t)blockIdx.z * in_bstride;
    out += (size_t)blockIdx.z * out_bstride;
    int c0 = blockIdx.x * 32, r0 = blockIdx.y * 32;
    int tx = threadIdx.x & 31, ty = threadIdx.x >> 5;
#pragma unroll
    for (int i = 0; i < 4; ++i) {
        int r = r0 + ty + 8 * i;
        tile[ty + 8 * i][tx] = *(const unsigned short*)(in + (size_t)r * in_stride + in_col0 + c0 + tx);
    }
    __syncthreads();
#pragma unroll
    for (int i = 0; i < 4; ++i) {
        int cc = c0 + ty + 8 * i, rr = r0 + tx;
        *(unsigned short*)(out + (size_t)cc * R + rr) = tile[tx][ty + 8 * i];
    }
}

// ---------- gate + transpose: ud1t[b](1024 x 2048) -> ud1[b](2048 x 1024), gated by u from uv (t,c) ----------
__global__ void k_gate_transpose(const bf16* __restrict__ ud1t, const bf16* __restrict__ uv,
                                 bf16* __restrict__ out)
{
    __shared__ float tile[32][33];
    const int b = blockIdx.z;
    int c0 = blockIdx.x * 32, t0 = blockIdx.y * 32;
    int tx = threadIdx.x & 31, ty = threadIdx.x >> 5;
#pragma unroll
    for (int i = 0; i < 4; ++i) {
        int cc = c0 + ty + 8 * i;
        tile[ty + 8 * i][tx] = __bfloat162float(ud1t[((size_t)b * 1024 + cc) * 2048 + t0 + tx]);
    }
    __syncthreads();
#pragma unroll
    for (int i = 0; i < 4; ++i) {
        int t = t0 + ty + 8 * i, c = c0 + tx;
        float u = __bfloat162float(uv[((size_t)b * 2048 + t) * 2048 + c]);
        out[((size_t)b * 2048 + t) * 1024 + c] = __float2bfloat16(tile[tx][ty + 8 * i] * u);
    }
}

// ---------- block reduction over 512 elems held 2-per-thread by 256 threads ----------
__device__ inline float block_sum_512(float v)
{
#pragma unroll
    for (int m = 32; m >= 1; m >>= 1) v += __shfl_xor(v, m, 64);
    __shared__ float ws[4];
    if ((threadIdx.x & 63) == 0) ws[threadIdx.x >> 6] = v;
    __syncthreads();
    return ws[0] + ws[1] + ws[2] + ws[3];
}

// ---------- x -> srms(x) as bf16 (rows of 512) ----------
__global__ void k_rms_x(const float* __restrict__ x, bf16* __restrict__ xn)
{
    int row = blockIdx.x, t = threadIdx.x;
    const float* xr = x + (size_t)row * 512;
    float a = xr[t], b = xr[t + 256];
    float tot = block_sum_512(a * a + b * b);
    float s = 1.f / (sqrtf(tot * (1.f / 512.f)) + 1e-8f);
    bf16* o = xn + (size_t)row * 512;
    o[t] = __float2bfloat16(a * s);
    o[t + 256] = __float2bfloat16(b * s);
}

// ---------- fully fused positional-filter MLP (v2: LDS-staged weights) ----------
// 128 blocks x 16 positions. Hidden state ping-pongs in LDS. Weights staged
// per 32-K slice into a double-buffered LDS tile by all 256 threads (coalesced
// uint4, held in regs across the MFMA burst) — fixes R5's VGPR-starved
// per-wave prefetch that made the kernel latency-bound (83 us, 2% busy).
__global__ __launch_bounds__(256, 1) void k_mlp_fused(
    const float* __restrict__ Wp, const float* __restrict__ bp,
    const bf16* __restrict__ W1t, const float* __restrict__ b1,
    const bf16* __restrict__ W2t, const float* __restrict__ b2,
    const bf16* __restrict__ W3t, const float* __restrict__ b3,
    const bf16* __restrict__ Wzt, const float* __restrict__ bz,
    bf16* __restrict__ ab)
{
    constexpr int LD = 520;   // X row stride (u16)
    constexpr int BLD = 40;   // B-tile row stride (u16): 32 + 8 pad, 80 B (16B-aligned)
    __shared__ unsigned short X[2][16][LD];
    __shared__ unsigned short Bs[2][512 * BLD];
    __shared__ float sq[16][17];
    __shared__ float red[4][16];
    __shared__ float scale[16];

    const int tid = threadIdx.x, lane = tid & 63, w = tid >> 6;
    const int lm = lane & 15, lq = lane >> 4;
    const int posBase = blockIdx.x * 16;
    const int wbase = w * 128;

    // stage 0: X[0][r][:] = relu(srms(pos*Wp + bp))
    {
        const int r = tid >> 4;
        const int c0 = (tid & 15) * 32;
        float vals[32];
        float ssq = 0.f;
        const float fp = (float)(posBase + r);
#pragma unroll
        for (int e = 0; e < 32; ++e) {
            float z = fp * Wp[c0 + e] + bp[c0 + e];
            vals[e] = z;
            ssq += z * z;
        }
        sq[r][tid & 15] = ssq;
        __syncthreads();
        float tot = 0.f;
#pragma unroll
        for (int i = 0; i < 16; ++i) tot += sq[r][i];
        float s = 1.f / (sqrtf(tot * (1.f / 512.f)) + 1e-8f);
        unsigned int* xrow = (unsigned int*)&X[0][r][c0];
#pragma unroll
        for (int e = 0; e < 16; ++e)
            xrow[e] = packbf2(fmaxf(vals[2 * e] * s, 0.f), fmaxf(vals[2 * e + 1] * s, 0.f));
    }

    // one 512-col x 512-K GEMM pass: acc[nj] covers cols wbase + nj*16 + lm
    auto layer_mm = [&](const bf16* Bt, f32x4* acc, int cur) {
        {   // prologue: stage slice 0 into buf 0
            uint4 regs[8];
#pragma unroll
            for (int r = 0; r < 8; ++r) {
                int j = r * 256 + tid;
                int row = j >> 2, ki = (j & 3) * 8;
                regs[r] = *(const uint4*)(const void*)(Bt + (size_t)row * 512 + ki);
            }
#pragma unroll
            for (int r = 0; r < 8; ++r) {
                int j = r * 256 + tid;
                int row = j >> 2, ki = (j & 3) * 8;
                *(uint4*)(void*)&Bs[0][row * BLD + ki] = regs[r];
            }
        }
        __syncthreads();
        for (int ks = 0; ks < 16; ++ks) {
            const int buf = ks & 1;
            uint4 regs[8];
            if (ks < 15) {
                const int k1 = (ks + 1) * 32;
#pragma unroll
                for (int r = 0; r < 8; ++r) {
                    int j = r * 256 + tid;
                    int row = j >> 2, ki = (j & 3) * 8;
                    regs[r] = *(const uint4*)(const void*)(Bt + (size_t)row * 512 + k1 + ki);
                }
            }
            bf16x8 afr = *(const bf16x8*)(const void*)&X[cur][lm][ks * 32 + lq * 8];
#pragma unroll
            for (int nj = 0; nj < 8; ++nj) {
                bf16x8 bfr = *(const bf16x8*)(const void*)&Bs[buf][(wbase + nj * 16 + lm) * BLD + lq * 8];
                acc[nj] = __builtin_amdgcn_mfma_f32_16x16x32_bf16(afr, bfr, acc[nj], 0, 0, 0);
            }
            if (ks < 15) {
#pragma unroll
                for (int r = 0; r < 8; ++r) {
                    int j = r * 256 + tid;
                    int row = j >> 2, ki = (j & 3) * 8;
                    *(uint4*)(void*)&Bs[buf ^ 1][row * BLD + ki] = regs[r];
                }
            }
            __syncthreads();
        }
    };

    const bf16* Ws[3] = {W1t, W2t, W3t};
    const float* bs[3] = {b1, b2, b3};
    int cur = 0;

    for (int l = 0; l < 3; ++l) {
        f32x4 acc[8];
#pragma unroll
        for (int i = 0; i < 8; ++i) acc[i] = (f32x4){0.f, 0.f, 0.f, 0.f};
        layer_mm(Ws[l], acc, cur);
        // bias BEFORE srms
#pragma unroll
        for (int nj = 0; nj < 8; ++nj) {
            float bb = bs[l][wbase + nj * 16 + lm];
#pragma unroll
            for (int r = 0; r < 4; ++r) acc[nj][r] += bb;
        }
        float pr[4] = {0.f, 0.f, 0.f, 0.f};
#pragma unroll
        for (int nj = 0; nj < 8; ++nj)
#pragma unroll
            for (int r = 0; r < 4; ++r) pr[r] += acc[nj][r] * acc[nj][r];
#pragma unroll
        for (int m = 1; m < 16; m <<= 1)
#pragma unroll
            for (int r = 0; r < 4; ++r) pr[r] += __shfl_xor(pr[r], m);
        if (lm == 0)
#pragma unroll
            for (int r = 0; r < 4; ++r) red[w][lq * 4 + r] = pr[r];
        __syncthreads();
        if (tid < 16) {
            float tot = red[0][tid] + red[1][tid] + red[2][tid] + red[3][tid];
            scale[tid] = 1.f / (sqrtf(tot * (1.f / 512.f)) + 1e-8f);
        }
        __syncthreads();
        const int nxt = cur ^ 1;
#pragma unroll
        for (int nj = 0; nj < 8; ++nj) {
            int col = wbase + nj * 16 + lm;
#pragma unroll
            for (int r = 0; r < 4; ++r) {
                int row = lq * 4 + r;
                float z = fmaxf(acc[nj][r] * scale[row], 0.f);
                *(unsigned short*)&X[nxt][row][col] = bf16_bits(z);
            }
        }
        cur = nxt;
    }

    // final layer: N=1024 as two 512-row halves; epilogue = +bz, *gamma^pos
    __syncthreads();
#pragma unroll
    for (int half = 0; half < 2; ++half) {
        f32x4 acc[8];
#pragma unroll
        for (int i = 0; i < 8; ++i) acc[i] = (f32x4){0.f, 0.f, 0.f, 0.f};
        layer_mm(Wzt + (size_t)half * 512 * 512, acc, cur);
#pragma unroll
        for (int nj = 0; nj < 8; ++nj) {
            int col = half * 512 + wbase + nj * 16 + lm;
            float bb = bz[col];
#pragma unroll
            for (int r = 0; r < 4; ++r) {
                int row = lq * 4 + r;
                int pos = posBase + row;
                float z = (acc[nj][r] + bb) * exp2f((float)pos * GAMMA_LOG2);
                ab[(size_t)pos * 1024 + col] = __float2bfloat16(z);
            }
        }
    }
}

// ---------- MFMA bf16 GEMM: A (MxK) row-major, Bt (NxK) row-major ----------
enum { EPI_SILU_BF16 = 0, EPI_BIAS_ADD_F32 = 3 };

template <int BM, int BN, int WM, int WN, int EPI>
__global__ __launch_bounds__(256, 2) void k_gemm(
    const bf16* __restrict__ A, const bf16* __restrict__ Bt,
    const float* __restrict__ bias0, const float* __restrict__ bias1, int bsplit,
    const float* __restrict__ addsrc, void* __restrict__ outp,
    int M, int N, int K)
{
    constexpr int BK = 32, LDT = BK + 8;
    constexpr int MI = WM / 16, NJ = WN / 16;
    constexpr int WCOLS = BN / WN;
    __shared__ unsigned short As[BM * LDT];
    __shared__ unsigned short Bs[BN * LDT];
    const int tid = threadIdx.x;
    const int lane = tid & 63, w = tid >> 6;
    const int wm = (w / WCOLS) * WM, wn = (w % WCOLS) * WN;
    const int lm = lane & 15, lq = lane >> 4;
    const long rowBase = (long)blockIdx.x * BM, colBase = (long)blockIdx.y * BN;

    f32x4 acc[MI][NJ];
    f32x4 zz = {0.f, 0.f, 0.f, 0.f};
#pragma unroll
    for (int i = 0; i < MI; ++i)
#pragma unroll
        for (int j = 0; j < NJ; ++j) acc[i][j] = zz;

    for (int k0 = 0; k0 < K; k0 += BK) {
#pragma unroll
        for (int i = 0; i < BM / 64; ++i) {
            int idx = (i * 256 + tid) * 8;
            int r = idx >> 5, kk = idx & 31;
            *(uint4*)(void*)(As + r * LDT + kk) =
                *(const uint4*)(const void*)(A + (rowBase + r) * K + k0 + kk);
        }
#pragma unroll
        for (int i = 0; i < BN / 64; ++i) {
            int idx = (i * 256 + tid) * 8;
            int r = idx >> 5, kk = idx & 31;
            *(uint4*)(void*)(Bs + r * LDT + kk) =
                *(const uint4*)(const void*)(Bt + (colBase + r) * K + k0 + kk);
        }
        __syncthreads();
        bf16x8 af[MI], bfr[NJ];
#pragma unroll
        for (int mi = 0; mi < MI; ++mi)
            af[mi] = *(const bf16x8*)(const void*)(As + (wm + mi * 16 + lm) * LDT + lq * 8);
#pragma unroll
        for (int nj = 0; nj < NJ; ++nj)
            bfr[nj] = *(const bf16x8*)(const void*)(Bs + (wn + nj * 16 + lm) * LDT + lq * 8);
#pragma unroll
        for (int mi = 0; mi < MI; ++mi)
#pragma unroll
            for (int nj = 0; nj < NJ; ++nj)
                acc[mi][nj] = __builtin_amdgcn_mfma_f32_16x16x32_bf16(af[mi], bfr[nj], acc[mi][nj], 0, 0, 0);
        __syncthreads();
    }

#pragma unroll
    for (int mi = 0; mi < MI; ++mi)
#pragma unroll
        for (int nj = 0; nj < NJ; ++nj) {
            long col = colBase + wn + nj * 16 + lm;
#pragma unroll
            for (int r = 0; r < 4; ++r) {
                long row = rowBase + wm + mi * 16 + lq * 4 + r;
                float z = acc[mi][nj][r];
                size_t off = (size_t)row * N + col;
                if constexpr (EPI == EPI_SILU_BF16) {
                    float bb = (col < bsplit) ? bias0[col] : bias1[col - bsplit];
                    z += bb;
                    z = z / (1.f + __expf(-z));
                    ((bf16*)outp)[off] = __float2bfloat16(z);
                } else {  // EPI_BIAS_ADD_F32: + bias + residual x
                    ((float*)outp)[off] = z + bias0[col] + addsrc[off];
                }
            }
        }
}

// ---------- Toeplitz-MFMA depthwise causal conv (v2) ----------
// Block = 1 channel x 4 batches (one wave per batch). The filter a is staged
// REVERSED in 2 parity-shifted LDS copies so every A-fragment is 4 consecutive
// dwords at a 4B-aligned address (ds_read2_b32) — no scalar u16 gathers.
// v is staged with stride-24 u16 per 16-elem tile so B-fragment ds_read_b128
// has only 2-way (free) bank aliasing.
// afrag[j] = a[W-j], W = 16*dd + 16*h + lm - p0;  ar[x] = a[2047-x] (0 for x>2047)
// => afrag[j] = ar[S+j], S = 2047 - W; copy k = S mod 2 = (lm+1)&1 per lane.
__global__ __launch_bounds__(256, 4) void k_conv_mfma(
    const bf16* __restrict__ vt, const bf16* __restrict__ at, bf16* __restrict__ ud1t)
{
    __shared__ unsigned short ash2[2][2068];  // reversed filter, 2 shifted copies
    __shared__ unsigned short vsh[4][3072];   // per-batch v, stride 24 per 16-elem tile

    const int tid = threadIdx.x, lane = tid & 63, w = tid >> 6;
    const int c = blockIdx.x;

    // build reversed shifted copies of a (shared by all 4 waves)
    {
        const unsigned short* asrc = (const unsigned short*)(at + (size_t)c * 2048);
        for (int i = tid; i < 2068; i += 256) {
#pragma unroll
            for (int k = 0; k < 2; ++k) {
                int src = 2047 - i - k;
                ash2[k][i] = (src >= 0) ? asrc[src] : (unsigned short)0;
            }
        }
    }
    // stage own batch's v (swizzled stride-24)
    {
        const bf16* vsrc = vt + ((size_t)w * 1024 + c) * 2048;
#pragma unroll
        for (int q = 0; q < 4; ++q) {
            int li = q * 64 + lane;
            int tile = li >> 1, hf = li & 1;
            *(uint4*)(void*)&vsh[w][tile * 24 + hf * 8] =
                *(const uint4*)(const void*)(vsrc + li * 8);
        }
    }
    __syncthreads();

    const int lm = lane & 15, lq = lane >> 4;
    const int h = lq >> 1, p0 = (lq & 1) * 8;
    const int kcopy = (lm + 1) & 1;
    // lane base (u16 index, even) at dd=126: 31 - 16h - lm + p0 - kcopy
    const int base = 31 - 16 * h - lm + p0 - kcopy;
    const unsigned int* aw = (const unsigned int*)(void*)&ash2[kcopy][0] + (base >> 1);
    const unsigned short* vw = &vsh[w][0];

    f32x4 acc[8];
    f32x4 zz = {0.f, 0.f, 0.f, 0.f};
#pragma unroll
    for (int i = 0; i < 8; ++i) acc[i] = zz;
    const bf16x8 zfrag = (bf16x8)(short)0;

    for (int dt = 0; dt < 8; ++dt) {
#pragma unroll
        for (int d2 = 0; d2 < 16; d2 += 2) {
            const int dd = dt * 16 + d2;
            const int m16 = (63 - (dd >> 1)) * 16;  // dword offset of this step's afrag
            union { unsigned int u[4]; bf16x8 v; } af;
            af.u[0] = aw[m16 + 0];
            af.u[1] = aw[m16 + 1];
            af.u[2] = aw[m16 + 2];
            af.u[3] = aw[m16 + 3];
            const int tb = lm - dd - h;
            for (int jg = dt; jg < 8; ++jg) {
                int tile = jg * 16 + tb;
                int T = tile > 0 ? tile : 0;
                bf16x8 vf = *(const bf16x8*)(const void*)(vw + T * 24 + p0);
                if (tile < 0) vf = zfrag;
                acc[jg] = __builtin_amdgcn_mfma_f32_16x16x32_bf16(af.v, vf, acc[jg], 0, 0, 0);
            }
        }
    }

    __syncthreads();  // ash2 is shared across waves; drain before reuse as staging
    // epilogue: D col=lm (jc), row=lq*4+r (i) -> t = jc*16+i; reshuffle via LDS, write t-contiguous
    float* stg = (float*)(void*)((char*)(void*)&ash2[0][0] + w * 1024);
    bf16* dst = ud1t + ((size_t)w * 1024 + c) * 2048;
#pragma unroll
    for (int jg = 0; jg < 8; ++jg) {
        *(f32x4*)(void*)&stg[lm * 16 + lq * 4] = acc[jg];
        f32x4 vv = *(const f32x4*)(const void*)&stg[lane * 4];  // same-wave DS ordering
        uint2 o;
        o.x = packbf2(vv.x, vv.y);
        o.y = packbf2(vv.z, vv.w);
        *(uint2*)(void*)(dst + jg * 256 + lane * 4) = o;
    }
}

extern "C" void kernel_launch(void* const* d_in, const int* in_sizes, int n_in,
                              void* d_out, int out_size, void* d_ws, size_t ws_size,
                              hipStream_t stream)
{
    const float* x  = (const float*)d_in[0];
    const float* Wu = (const float*)d_in[1];
    const float* bu = (const float*)d_in[2];
    const float* Wv = (const float*)d_in[3];
    const float* bv = (const float*)d_in[4];
    const float* Wo = (const float*)d_in[5];
    const float* bo = (const float*)d_in[6];
    const float* Wp = (const float*)d_in[7];
    const float* bp = (const float*)d_in[8];
    const float* W1 = (const float*)d_in[9];
    const float* b1 = (const float*)d_in[10];
    const float* W2 = (const float*)d_in[11];
    const float* b2 = (const float*)d_in[12];
    const float* W3 = (const float*)d_in[13];
    const float* b3 = (const float*)d_in[14];
    const float* Wz = (const float*)d_in[15];
    const float* bz = (const float*)d_in[16];

    char* p = (char*)d_ws;
    auto carve = [&](size_t bytes) { void* q = (void*)p; p += (bytes + 255) & ~(size_t)255; return q; };
    bf16*  xn   = (bf16*)carve((size_t)8192 * 512 * 2);
    bf16*  Wuvt = (bf16*)carve((size_t)2048 * 512 * 2);
    bf16*  Wot  = (bf16*)carve((size_t)512 * 1024 * 2);
    bf16*  W1t  = (bf16*)carve((size_t)512 * 512 * 2);
    bf16*  W2t  = (bf16*)carve((size_t)512 * 512 * 2);
    bf16*  W3t  = (bf16*)carve((size_t)512 * 512 * 2);
    bf16*  Wzt  = (bf16*)carve((size_t)1024 * 512 * 2);
    bf16*  uvb  = (bf16*)carve((size_t)8192 * 2048 * 2);      // [u | v] silu outputs (t, c)
    bf16*  ud1  = (bf16*)carve((size_t)8192 * 1024 * 2);      // u * conv, (t, c)
    bf16*  ab   = (bf16*)carve((size_t)2048 * 1024 * 2);      // decayed filter a[k,c]
    bf16*  vtb  = (bf16*)carve((size_t)4 * 1024 * 2048 * 2);  // v (b,c,t)
    bf16*  atb  = (bf16*)carve((size_t)1024 * 2048 * 2);      // a (c,k)
    bf16*  ud1t = (bf16*)carve((size_t)4 * 1024 * 2048 * 2);  // conv result (b,c,t)

    // merged weight prep (7 transposes, one launch)
    PrepArgs pa;
    const float* srcs[7] = {Wu, Wv, Wo, W1, W2, W3, Wz};
    bf16* dsts[7] = {Wuvt, Wuvt + (size_t)1024 * 512, Wot, W1t, W2t, W3t, Wzt};
    int Rs[7] = {512, 512, 1024, 512, 512, 512, 512};
    int Cs[7] = {1024, 1024, 512, 512, 512, 512, 1024};
    int acc_t = 0;
    for (int i = 0; i < 7; ++i) {
        pa.src[i] = srcs[i]; pa.dst[i] = dsts[i]; pa.R[i] = Rs[i]; pa.C[i] = Cs[i];
        pa.pfx[i] = acc_t;
        acc_t += (Rs[i] / 32) * (Cs[i] / 32);
    }
    pa.pfx[7] = acc_t;  // 2816
    k_prep<<<acc_t, 256, 0, stream>>>(pa);

    k_rms_x<<<8192, 256, 0, stream>>>(x, xn);

    // fused positional MLP -> ab[k, c]
    k_mlp_fused<<<128, 256, 0, stream>>>(Wp, bp, W1t, b1, W2t, b2, W3t, b3, Wzt, bz, ab);

    // a -> (c, k)
    k_transpose_bf16<<<dim3(32, 64, 1), 256, 0, stream>>>(
        ab, atb, 2048, 1024, 1024, 0, 0, 0);

    // u|v = silu(xn @ [Wu|Wv] + [bu|bv])
    k_gemm<128, 128, 64, 64, EPI_SILU_BF16><<<dim3(64, 16), 256, 0, stream>>>(
        xn, Wuvt, bu, bv, 1024, nullptr, uvb, 8192, 2048, 512);

    // v -> (b, c, t)
    k_transpose_bf16<<<dim3(32, 64, 4), 256, 0, stream>>>(
        uvb, vtb, 2048, 1024, 2048, 1024, (size_t)2048 * 2048, (size_t)1024 * 2048);

    // causal depthwise conv via Toeplitz-MFMA (block = channel x 4 batches)
    k_conv_mfma<<<dim3(1024), 256, 0, stream>>>(vtb, atb, ud1t);

    // gate by u and transpose back to (t, c)
    k_gate_transpose<<<dim3(32, 64, 4), 256, 0, stream>>>(ud1t, uvb, ud1);

    // y = ud1 @ Wo + bo + x
    k_gemm<128, 128, 64, 64, EPI_BIAS_ADD_F32><<<dim3(64, 4), 256, 0, stream>>>(
        ud1, Wot, bo, nullptr, 0, x, d_out, 8192, 512, 1024);
}

// Round 7
// 314.584 us; speedup vs baseline: 1.3287x; 1.3287x over previous
//
#include <hip/hip_runtime.h>
#include <hip/hip_bf16.h>
#include <math.h>

using bf16 = __hip_bfloat16;
typedef short bf16x8 __attribute__((ext_vector_type(8)));
typedef float f32x4 __attribute__((ext_vector_type(4)));

#define GAMMA_LOG2 (-0.0014434688536725045f)  // log2(0.999)

union Bf16Bits { bf16 h; unsigned short s; };

__device__ inline unsigned short bf16_bits(float z)
{
    Bf16Bits u;
    u.h = __float2bfloat16(z);
    return u.s;
}

__device__ inline unsigned int packbf2(float a, float b)
{
    return (unsigned int)bf16_bits(a) | ((unsigned int)bf16_bits(b) << 16);
}

// ---------- merged weight prep: 7 fp32 (R x C) -> bf16 (C x R) transposes in one launch ----------
struct PrepArgs {
    const float* src[7];
    bf16* dst[7];
    int R[7];
    int C[7];
    int pfx[8];  // tile prefix sums
};

__global__ void k_prep(PrepArgs pa)
{
    __shared__ float tile[32][33];
    int bid = blockIdx.x;
    int seg = 0;
    while (bid >= pa.pfx[seg + 1]) ++seg;
    int local = bid - pa.pfx[seg];
    int R = pa.R[seg], C = pa.C[seg];
    int ctiles = C >> 5;
    int c0 = (local % ctiles) * 32, r0 = (local / ctiles) * 32;
    const float* in = pa.src[seg];
    bf16* out = pa.dst[seg];
    int tx = threadIdx.x & 31, ty = threadIdx.x >> 5;
#pragma unroll
    for (int i = 0; i < 4; ++i) {
        int r = r0 + ty + 8 * i;
        tile[ty + 8 * i][tx] = in[(size_t)r * C + c0 + tx];
    }
    __syncthreads();
#pragma unroll
    for (int i = 0; i < 4; ++i) {
        int cc = c0 + ty + 8 * i, rr = r0 + tx;
        out[(size_t)cc * R + rr] = __float2bfloat16(tile[tx][ty + 8 * i]);
    }
}

// ---------- merged bf16 transposes: z<4 -> v slice of uvb[b] -> vtb[b]; z==4 -> ab -> atb ----------
__global__ void k_transpose5(const bf16* __restrict__ uvb, const bf16* __restrict__ ab,
                             bf16* __restrict__ vtb, bf16* __restrict__ atb)
{
    __shared__ unsigned short tile[32][33];
    const int z = blockIdx.z;
    const bf16* in;
    bf16* out;
    int in_stride, col0;
    if (z < 4) {
        in = uvb + (size_t)z * 2048 * 2048;
        out = vtb + (size_t)z * 1024 * 2048;
        in_stride = 2048;
        col0 = 1024;
    } else {
        in = ab;
        out = atb;
        in_stride = 1024;
        col0 = 0;
    }
    int c0 = blockIdx.x * 32, r0 = blockIdx.y * 32;
    int tx = threadIdx.x & 31, ty = threadIdx.x >> 5;
#pragma unroll
    for (int i = 0; i < 4; ++i) {
        int r = r0 + ty + 8 * i;
        tile[ty + 8 * i][tx] = *(const unsigned short*)(in + (size_t)r * in_stride + col0 + c0 + tx);
    }
    __syncthreads();
#pragma unroll
    for (int i = 0; i < 4; ++i) {
        int cc = c0 + ty + 8 * i, rr = r0 + tx;
        *(unsigned short*)(out + (size_t)cc * 2048 + rr) = tile[tx][ty + 8 * i];
    }
}

// ---------- gate + transpose: ud1t[b](1024 x 2048) -> ud1[b](2048 x 1024), gated by u from uv (t,c) ----------
__global__ void k_gate_transpose(const bf16* __restrict__ ud1t, const bf16* __restrict__ uv,
                                 bf16* __restrict__ out)
{
    __shared__ float tile[32][33];
    const int b = blockIdx.z;
    int c0 = blockIdx.x * 32, t0 = blockIdx.y * 32;
    int tx = threadIdx.x & 31, ty = threadIdx.x >> 5;
#pragma unroll
    for (int i = 0; i < 4; ++i) {
        int cc = c0 + ty + 8 * i;
        tile[ty + 8 * i][tx] = __bfloat162float(ud1t[((size_t)b * 1024 + cc) * 2048 + t0 + tx]);
    }
    __syncthreads();
#pragma unroll
    for (int i = 0; i < 4; ++i) {
        int t = t0 + ty + 8 * i, c = c0 + tx;
        float u = __bfloat162float(uv[((size_t)b * 2048 + t) * 2048 + c]);
        out[((size_t)b * 2048 + t) * 1024 + c] = __float2bfloat16(tile[tx][ty + 8 * i] * u);
    }
}

// ---------- block reduction over 512 elems held 2-per-thread by 256 threads ----------
__device__ inline float block_sum_512(float v)
{
#pragma unroll
    for (int m = 32; m >= 1; m >>= 1) v += __shfl_xor(v, m, 64);
    __shared__ float ws[4];
    if ((threadIdx.x & 63) == 0) ws[threadIdx.x >> 6] = v;
    __syncthreads();
    return ws[0] + ws[1] + ws[2] + ws[3];
}

// ---------- x -> srms(x) as bf16 (rows of 512) ----------
__global__ void k_rms_x(const float* __restrict__ x, bf16* __restrict__ xn)
{
    int row = blockIdx.x, t = threadIdx.x;
    const float* xr = x + (size_t)row * 512;
    float a = xr[t], b = xr[t + 256];
    float tot = block_sum_512(a * a + b * b);
    float s = 1.f / (sqrtf(tot * (1.f / 512.f)) + 1e-8f);
    bf16* o = xn + (size_t)row * 512;
    o[t] = __float2bfloat16(a * s);
    o[t + 256] = __float2bfloat16(b * s);
}

// ---------- combined kernel: blocks [0,128) = fused positional MLP (latency-bound leg),
//                             blocks [128,1152) = uv GEMM (throughput leg).
// The two are independent; co-scheduling hides the MLP's ~80 us of idle-wave latency
// under the GEMM's MFMA work instead of serializing two launches.
__global__ __launch_bounds__(256, 2) void k_uv_mlp(
    const bf16* __restrict__ A, const bf16* __restrict__ Bt,   // xn, Wuvt (2048 x 512)
    const float* __restrict__ bu, const float* __restrict__ bv,
    const float* __restrict__ Wp, const float* __restrict__ bp,
    const bf16* __restrict__ W1t, const float* __restrict__ b1,
    const bf16* __restrict__ W2t, const float* __restrict__ b2,
    const bf16* __restrict__ W3t, const float* __restrict__ b3,
    const bf16* __restrict__ Wzt, const float* __restrict__ bz,
    bf16* __restrict__ uvb, bf16* __restrict__ ab)
{
    // GEMM leg LDS
    __shared__ unsigned short As[128 * 40];
    __shared__ unsigned short Bs[128 * 40];
    // MLP leg LDS (X is in-place: all reads of a layer complete before the
    // post-reduction barrier that precedes the writes)
    __shared__ unsigned short X[16][520];
    __shared__ float sq[16][17];
    __shared__ float red[4][16];
    __shared__ float scale[16];

    const int tid = threadIdx.x, lane = tid & 63, w = tid >> 6;
    const int lm = lane & 15, lq = lane >> 4;

    if (blockIdx.x < 128) {
        // ================= MLP leg =================
        const int posBase = blockIdx.x * 16;
        const int wbase = w * 128;

        // stage 0: X[r][:] = relu(srms(pos*Wp + bp))
        {
            const int r = tid >> 4;
            const int c0 = (tid & 15) * 32;
            float vals[32];
            float ssq = 0.f;
            const float fp = (float)(posBase + r);
#pragma unroll
            for (int e = 0; e < 32; ++e) {
                float z = fp * Wp[c0 + e] + bp[c0 + e];
                vals[e] = z;
                ssq += z * z;
            }
            sq[r][tid & 15] = ssq;
            __syncthreads();
            float tot = 0.f;
#pragma unroll
            for (int i = 0; i < 16; ++i) tot += sq[r][i];
            float s = 1.f / (sqrtf(tot * (1.f / 512.f)) + 1e-8f);
            unsigned int* xrow = (unsigned int*)&X[r][c0];
#pragma unroll
            for (int e = 0; e < 16; ++e)
                xrow[e] = packbf2(fmaxf(vals[2 * e] * s, 0.f), fmaxf(vals[2 * e + 1] * s, 0.f));
        }

        const bf16* Ws[3] = {W1t, W2t, W3t};
        const float* bs[3] = {b1, b2, b3};

        for (int l = 0; l < 3; ++l) {
            __syncthreads();
            const bf16* Bw = Ws[l];
            f32x4 acc[8];
#pragma unroll
            for (int i = 0; i < 8; ++i) acc[i] = (f32x4){0.f, 0.f, 0.f, 0.f};

            bf16x8 bufA[2];
            bf16x8 bufB[2][8];
            bufA[0] = *(const bf16x8*)(const void*)&X[lm][lq * 8];
#pragma unroll
            for (int nj = 0; nj < 8; ++nj)
                bufB[0][nj] = *(const bf16x8*)(const void*)(Bw + (size_t)(wbase + nj * 16 + lm) * 512 + lq * 8);
#pragma unroll
            for (int ks = 0; ks < 16; ++ks) {
                const int p = ks & 1, q = p ^ 1;
                if (ks < 15) {
                    const int k1 = (ks + 1) * 32;
                    bufA[q] = *(const bf16x8*)(const void*)&X[lm][k1 + lq * 8];
#pragma unroll
                    for (int nj = 0; nj < 8; ++nj)
                        bufB[q][nj] = *(const bf16x8*)(const void*)(Bw + (size_t)(wbase + nj * 16 + lm) * 512 + k1 + lq * 8);
                }
#pragma unroll
                for (int nj = 0; nj < 8; ++nj)
                    acc[nj] = __builtin_amdgcn_mfma_f32_16x16x32_bf16(bufA[p], bufB[p][nj], acc[nj], 0, 0, 0);
            }
            // bias BEFORE srms
#pragma unroll
            for (int nj = 0; nj < 8; ++nj) {
                float bb = bs[l][wbase + nj * 16 + lm];
#pragma unroll
                for (int r = 0; r < 4; ++r) acc[nj][r] += bb;
            }
            float pr[4] = {0.f, 0.f, 0.f, 0.f};
#pragma unroll
            for (int nj = 0; nj < 8; ++nj)
#pragma unroll
                for (int r = 0; r < 4; ++r) pr[r] += acc[nj][r] * acc[nj][r];
#pragma unroll
            for (int m = 1; m < 16; m <<= 1)
#pragma unroll
                for (int r = 0; r < 4; ++r) pr[r] += __shfl_xor(pr[r], m);
            if (lm == 0)
#pragma unroll
                for (int r = 0; r < 4; ++r) red[w][lq * 4 + r] = pr[r];
            __syncthreads();   // also guarantees all X reads of this layer are done
            if (tid < 16) {
                float tot = red[0][tid] + red[1][tid] + red[2][tid] + red[3][tid];
                scale[tid] = 1.f / (sqrtf(tot * (1.f / 512.f)) + 1e-8f);
            }
            __syncthreads();
#pragma unroll
            for (int nj = 0; nj < 8; ++nj) {
                int col = wbase + nj * 16 + lm;
#pragma unroll
                for (int r = 0; r < 4; ++r) {
                    int row = lq * 4 + r;
                    float z = fmaxf(acc[nj][r] * scale[row], 0.f);
                    *(unsigned short*)&X[row][col] = bf16_bits(z);
                }
            }
        }

        // final layer: N=1024 as two 128-col passes per wave; epilogue = +bz, *gamma^pos
        __syncthreads();
#pragma unroll
        for (int half = 0; half < 2; ++half) {
            const int cb = w * 256 + half * 128;
            f32x4 acc[8];
#pragma unroll
            for (int i = 0; i < 8; ++i) acc[i] = (f32x4){0.f, 0.f, 0.f, 0.f};
            bf16x8 bufA[2];
            bf16x8 bufB[2][8];
            bufA[0] = *(const bf16x8*)(const void*)&X[lm][lq * 8];
#pragma unroll
            for (int nj = 0; nj < 8; ++nj)
                bufB[0][nj] = *(const bf16x8*)(const void*)(Wzt + (size_t)(cb + nj * 16 + lm) * 512 + lq * 8);
#pragma unroll
            for (int ks = 0; ks < 16; ++ks) {
                const int p = ks & 1, q = p ^ 1;
                if (ks < 15) {
                    const int k1 = (ks + 1) * 32;
                    bufA[q] = *(const bf16x8*)(const void*)&X[lm][k1 + lq * 8];
#pragma unroll
                    for (int nj = 0; nj < 8; ++nj)
                        bufB[q][nj] = *(const bf16x8*)(const void*)(Wzt + (size_t)(cb + nj * 16 + lm) * 512 + k1 + lq * 8);
                }
#pragma unroll
                for (int nj = 0; nj < 8; ++nj)
                    acc[nj] = __builtin_amdgcn_mfma_f32_16x16x32_bf16(bufA[p], bufB[p][nj], acc[nj], 0, 0, 0);
            }
#pragma unroll
            for (int nj = 0; nj < 8; ++nj) {
                int col = cb + nj * 16 + lm;
                float bb = bz[col];
#pragma unroll
                for (int r = 0; r < 4; ++r) {
                    int row = lq * 4 + r;
                    int pos = posBase + row;
                    float z = (acc[nj][r] + bb) * exp2f((float)pos * GAMMA_LOG2);
                    ab[(size_t)pos * 1024 + col] = __float2bfloat16(z);
                }
            }
        }
        return;
    }

    // ================= GEMM leg: uv = silu(xn @ Wuvt + [bu|bv]) =================
    const int gid = (int)blockIdx.x - 128;
    const int wm = (w >> 1) * 64, wn = (w & 1) * 64;  // WCOLS = 2
    const long rowBase = (long)(gid & 63) * 128, colBase = (long)(gid >> 6) * 128;

    f32x4 acc[4][4];
    f32x4 zz = {0.f, 0.f, 0.f, 0.f};
#pragma unroll
    for (int i = 0; i < 4; ++i)
#pragma unroll
        for (int j = 0; j < 4; ++j) acc[i][j] = zz;

    for (int k0 = 0; k0 < 512; k0 += 32) {
#pragma unroll
        for (int i = 0; i < 2; ++i) {
            int idx = (i * 256 + tid) * 8;
            int r = idx >> 5, kk = idx & 31;
            *(uint4*)(void*)(As + r * 40 + kk) =
                *(const uint4*)(const void*)(A + (rowBase + r) * 512 + k0 + kk);
        }
#pragma unroll
        for (int i = 0; i < 2; ++i) {
            int idx = (i * 256 + tid) * 8;
            int r = idx >> 5, kk = idx & 31;
            *(uint4*)(void*)(Bs + r * 40 + kk) =
                *(const uint4*)(const void*)(Bt + (colBase + r) * 512 + k0 + kk);
        }
        __syncthreads();
        bf16x8 af[4], bfr[4];
#pragma unroll
        for (int mi = 0; mi < 4; ++mi)
            af[mi] = *(const bf16x8*)(const void*)(As + (wm + mi * 16 + lm) * 40 + lq * 8);
#pragma unroll
        for (int nj = 0; nj < 4; ++nj)
            bfr[nj] = *(const bf16x8*)(const void*)(Bs + (wn + nj * 16 + lm) * 40 + lq * 8);
#pragma unroll
        for (int mi = 0; mi < 4; ++mi)
#pragma unroll
            for (int nj = 0; nj < 4; ++nj)
                acc[mi][nj] = __builtin_amdgcn_mfma_f32_16x16x32_bf16(af[mi], bfr[nj], acc[mi][nj], 0, 0, 0);
        __syncthreads();
    }

#pragma unroll
    for (int mi = 0; mi < 4; ++mi)
#pragma unroll
        for (int nj = 0; nj < 4; ++nj) {
            long col = colBase + wn + nj * 16 + lm;
            float bb = (col < 1024) ? bu[col] : bv[col - 1024];
#pragma unroll
            for (int r = 0; r < 4; ++r) {
                long row = rowBase + wm + mi * 16 + lq * 4 + r;
                float z = acc[mi][nj][r] + bb;
                z = z / (1.f + __expf(-z));
                uvb[(size_t)row * 2048 + col] = __float2bfloat16(z);
            }
        }
}

// ---------- MFMA bf16 GEMM (out projection): A (MxK) row-major, Bt (NxK) row-major ----------
template <int BM, int BN, int WM, int WN>
__global__ __launch_bounds__(256, 2) void k_gemm_out(
    const bf16* __restrict__ A, const bf16* __restrict__ Bt,
    const float* __restrict__ bias0, const float* __restrict__ addsrc,
    float* __restrict__ outp, int M, int N, int K)
{
    constexpr int BK = 32, LDT = BK + 8;
    constexpr int MI = WM / 16, NJ = WN / 16;
    constexpr int WCOLS = BN / WN;
    __shared__ unsigned short As[BM * LDT];
    __shared__ unsigned short Bs[BN * LDT];
    const int tid = threadIdx.x;
    const int lane = tid & 63, w = tid >> 6;
    const int wm = (w / WCOLS) * WM, wn = (w % WCOLS) * WN;
    const int lm = lane & 15, lq = lane >> 4;
    const long rowBase = (long)blockIdx.x * BM, colBase = (long)blockIdx.y * BN;

    f32x4 acc[MI][NJ];
    f32x4 zz = {0.f, 0.f, 0.f, 0.f};
#pragma unroll
    for (int i = 0; i < MI; ++i)
#pragma unroll
        for (int j = 0; j < NJ; ++j) acc[i][j] = zz;

    for (int k0 = 0; k0 < K; k0 += BK) {
#pragma unroll
        for (int i = 0; i < BM / 64; ++i) {
            int idx = (i * 256 + tid) * 8;
            int r = idx >> 5, kk = idx & 31;
            *(uint4*)(void*)(As + r * LDT + kk) =
                *(const uint4*)(const void*)(A + (rowBase + r) * K + k0 + kk);
        }
#pragma unroll
        for (int i = 0; i < BN / 64; ++i) {
            int idx = (i * 256 + tid) * 8;
            int r = idx >> 5, kk = idx & 31;
            *(uint4*)(void*)(Bs + r * LDT + kk) =
                *(const uint4*)(const void*)(Bt + (colBase + r) * K + k0 + kk);
        }
        __syncthreads();
        bf16x8 af[MI], bfr[NJ];
#pragma unroll
        for (int mi = 0; mi < MI; ++mi)
            af[mi] = *(const bf16x8*)(const void*)(As + (wm + mi * 16 + lm) * LDT + lq * 8);
#pragma unroll
        for (int nj = 0; nj < NJ; ++nj)
            bfr[nj] = *(const bf16x8*)(const void*)(Bs + (wn + nj * 16 + lm) * LDT + lq * 8);
#pragma unroll
        for (int mi = 0; mi < MI; ++mi)
#pragma unroll
            for (int nj = 0; nj < NJ; ++nj)
                acc[mi][nj] = __builtin_amdgcn_mfma_f32_16x16x32_bf16(af[mi], bfr[nj], acc[mi][nj], 0, 0, 0);
        __syncthreads();
    }

#pragma unroll
    for (int mi = 0; mi < MI; ++mi)
#pragma unroll
        for (int nj = 0; nj < NJ; ++nj) {
            long col = colBase + wn + nj * 16 + lm;
#pragma unroll
            for (int r = 0; r < 4; ++r) {
                long row = rowBase + wm + mi * 16 + lq * 4 + r;
                size_t off = (size_t)row * N + col;
                outp[off] = acc[mi][nj][r] + bias0[col] + addsrc[off];
            }
        }
}

// ---------- Toeplitz-MFMA depthwise causal conv ----------
__global__ __launch_bounds__(256, 4) void k_conv_mfma(
    const bf16* __restrict__ vt, const bf16* __restrict__ at, bf16* __restrict__ ud1t)
{
    __shared__ unsigned short ash2[2][2068];  // reversed filter, 2 shifted copies
    __shared__ unsigned short vsh[4][3072];   // per-batch v, stride 24 per 16-elem tile

    const int tid = threadIdx.x, lane = tid & 63, w = tid >> 6;
    const int c = blockIdx.x;

    {
        const unsigned short* asrc = (const unsigned short*)(at + (size_t)c * 2048);
        for (int i = tid; i < 2068; i += 256) {
#pragma unroll
            for (int k = 0; k < 2; ++k) {
                int src = 2047 - i - k;
                ash2[k][i] = (src >= 0) ? asrc[src] : (unsigned short)0;
            }
        }
    }
    {
        const bf16* vsrc = vt + ((size_t)w * 1024 + c) * 2048;
#pragma unroll
        for (int q = 0; q < 4; ++q) {
            int li = q * 64 + lane;
            int tile = li >> 1, hf = li & 1;
            *(uint4*)(void*)&vsh[w][tile * 24 + hf * 8] =
                *(const uint4*)(const void*)(vsrc + li * 8);
        }
    }
    __syncthreads();

    const int lm = lane & 15, lq = lane >> 4;
    const int h = lq >> 1, p0 = (lq & 1) * 8;
    const int kcopy = (lm + 1) & 1;
    const int base = 31 - 16 * h - lm + p0 - kcopy;
    const unsigned int* aw = (const unsigned int*)(void*)&ash2[kcopy][0] + (base >> 1);
    const unsigned short* vw = &vsh[w][0];

    f32x4 acc[8];
    f32x4 zz = {0.f, 0.f, 0.f, 0.f};
#pragma unroll
    for (int i = 0; i < 8; ++i) acc[i] = zz;
    const bf16x8 zfrag = (bf16x8)(short)0;

    for (int dt = 0; dt < 8; ++dt) {
#pragma unroll
        for (int d2 = 0; d2 < 16; d2 += 2) {
            const int dd = dt * 16 + d2;
            const int m16 = (63 - (dd >> 1)) * 16;
            union { unsigned int u[4]; bf16x8 v; } af;
            af.u[0] = aw[m16 + 0];
            af.u[1] = aw[m16 + 1];
            af.u[2] = aw[m16 + 2];
            af.u[3] = aw[m16 + 3];
            const int tb = lm - dd - h;
            for (int jg = dt; jg < 8; ++jg) {
                int tile = jg * 16 + tb;
                int T = tile > 0 ? tile : 0;
                bf16x8 vf = *(const bf16x8*)(const void*)(vw + T * 24 + p0);
                if (tile < 0) vf = zfrag;
                acc[jg] = __builtin_amdgcn_mfma_f32_16x16x32_bf16(af.v, vf, acc[jg], 0, 0, 0);
            }
        }
    }

    __syncthreads();
    float* stg = (float*)(void*)((char*)(void*)&ash2[0][0] + w * 1024);
    bf16* dst = ud1t + ((size_t)w * 1024 + c) * 2048;
#pragma unroll
    for (int jg = 0; jg < 8; ++jg) {
        *(f32x4*)(void*)&stg[lm * 16 + lq * 4] = acc[jg];
        f32x4 vv = *(const f32x4*)(const void*)&stg[lane * 4];
        uint2 o;
        o.x = packbf2(vv.x, vv.y);
        o.y = packbf2(vv.z, vv.w);
        *(uint2*)(void*)(dst + jg * 256 + lane * 4) = o;
    }
}

extern "C" void kernel_launch(void* const* d_in, const int* in_sizes, int n_in,
                              void* d_out, int out_size, void* d_ws, size_t ws_size,
                              hipStream_t stream)
{
    const float* x  = (const float*)d_in[0];
    const float* Wu = (const float*)d_in[1];
    const float* bu = (const float*)d_in[2];
    const float* Wv = (const float*)d_in[3];
    const float* bv = (const float*)d_in[4];
    const float* Wo = (const float*)d_in[5];
    const float* bo = (const float*)d_in[6];
    const float* Wp = (const float*)d_in[7];
    const float* bp = (const float*)d_in[8];
    const float* W1 = (const float*)d_in[9];
    const float* b1 = (const float*)d_in[10];
    const float* W2 = (const float*)d_in[11];
    const float* b2 = (const float*)d_in[12];
    const float* W3 = (const float*)d_in[13];
    const float* b3 = (const float*)d_in[14];
    const float* Wz = (const float*)d_in[15];
    const float* bz = (const float*)d_in[16];

    char* p = (char*)d_ws;
    auto carve = [&](size_t bytes) { void* q = (void*)p; p += (bytes + 255) & ~(size_t)255; return q; };
    bf16*  xn   = (bf16*)carve((size_t)8192 * 512 * 2);
    bf16*  Wuvt = (bf16*)carve((size_t)2048 * 512 * 2);
    bf16*  Wot  = (bf16*)carve((size_t)512 * 1024 * 2);
    bf16*  W1t  = (bf16*)carve((size_t)512 * 512 * 2);
    bf16*  W2t  = (bf16*)carve((size_t)512 * 512 * 2);
    bf16*  W3t  = (bf16*)carve((size_t)512 * 512 * 2);
    bf16*  Wzt  = (bf16*)carve((size_t)1024 * 512 * 2);
    bf16*  uvb  = (bf16*)carve((size_t)8192 * 2048 * 2);      // [u | v] silu outputs (t, c)
    bf16*  ud1  = (bf16*)carve((size_t)8192 * 1024 * 2);      // u * conv, (t, c)
    bf16*  ab   = (bf16*)carve((size_t)2048 * 1024 * 2);      // decayed filter a[k,c]
    bf16*  vtb  = (bf16*)carve((size_t)4 * 1024 * 2048 * 2);  // v (b,c,t)
    bf16*  atb  = (bf16*)carve((size_t)1024 * 2048 * 2);      // a (c,k)
    bf16*  ud1t = (bf16*)carve((size_t)4 * 1024 * 2048 * 2);  // conv result (b,c,t)

    // merged weight prep (7 transposes, one launch)
    PrepArgs pa;
    const float* srcs[7] = {Wu, Wv, Wo, W1, W2, W3, Wz};
    bf16* dsts[7] = {Wuvt, Wuvt + (size_t)1024 * 512, Wot, W1t, W2t, W3t, Wzt};
    int Rs[7] = {512, 512, 1024, 512, 512, 512, 512};
    int Cs[7] = {1024, 1024, 512, 512, 512, 512, 1024};
    int acc_t = 0;
    for (int i = 0; i < 7; ++i) {
        pa.src[i] = srcs[i]; pa.dst[i] = dsts[i]; pa.R[i] = Rs[i]; pa.C[i] = Cs[i];
        pa.pfx[i] = acc_t;
        acc_t += (Rs[i] / 32) * (Cs[i] / 32);
    }
    pa.pfx[7] = acc_t;  // 2816
    k_prep<<<acc_t, 256, 0, stream>>>(pa);

    k_rms_x<<<8192, 256, 0, stream>>>(x, xn);

    // combined: uv GEMM + fused positional MLP (MLP blocks first for early dispatch)
    k_uv_mlp<<<1152, 256, 0, stream>>>(xn, Wuvt, bu, bv, Wp, bp,
                                       W1t, b1, W2t, b2, W3t, b3, Wzt, bz, uvb, ab);

    // v -> (b,c,t) and a -> (c,k) in one launch
    k_transpose5<<<dim3(32, 64, 5), 256, 0, stream>>>(uvb, ab, vtb, atb);

    // causal depthwise conv via Toeplitz-MFMA (block = channel x 4 batches)
    k_conv_mfma<<<dim3(1024), 256, 0, stream>>>(vtb, atb, ud1t);

    // gate by u and transpose back to (t, c)
    k_gate_transpose<<<dim3(32, 64, 4), 256, 0, stream>>>(ud1t, uvb, ud1);

    // y = ud1 @ Wo + bo + x
    k_gemm_out<128, 128, 64, 64><<<dim3(64, 4), 256, 0, stream>>>(
        ud1, Wot, bo, x, (float*)d_out, 8192, 512, 1024);
}

// Round 8
// 298.615 us; speedup vs baseline: 1.3997x; 1.0535x over previous
//
#include <hip/hip_runtime.h>
#include <hip/hip_bf16.h>
#include <math.h>

using bf16 = __hip_bfloat16;
typedef short bf16x8 __attribute__((ext_vector_type(8)));
typedef float f32x4 __attribute__((ext_vector_type(4)));

#define GAMMA_LOG2 (-0.0014434688536725045f)  // log2(0.999)

union Bf16Bits { bf16 h; unsigned short s; };
union VecU { uint4 q; unsigned short s[8]; };

__device__ inline unsigned short bf16_bits(float z)
{
    Bf16Bits u;
    u.h = __float2bfloat16(z);
    return u.s;
}

__device__ inline unsigned int packbf2(float a, float b)
{
    return (unsigned int)bf16_bits(a) | ((unsigned int)bf16_bits(b) << 16);
}

// ---------- weight prep: 3 fp32 (R x C) -> bf16 (C x R) transposes in one launch ----------
struct PrepArgs {
    const float* src[3];
    bf16* dst[3];
    int R[3];
    int C[3];
    int pfx[4];
};

__global__ void k_prep(PrepArgs pa)
{
    __shared__ float tile[32][33];
    int bid = blockIdx.x;
    int seg = 0;
    while (bid >= pa.pfx[seg + 1]) ++seg;
    int local = bid - pa.pfx[seg];
    int R = pa.R[seg], C = pa.C[seg];
    int ctiles = C >> 5;
    int c0 = (local % ctiles) * 32, r0 = (local / ctiles) * 32;
    const float* in = pa.src[seg];
    bf16* out = pa.dst[seg];
    int tx = threadIdx.x & 31, ty = threadIdx.x >> 5;
#pragma unroll
    for (int i = 0; i < 4; ++i) {
        int r = r0 + ty + 8 * i;
        tile[ty + 8 * i][tx] = in[(size_t)r * C + c0 + tx];
    }
    __syncthreads();
#pragma unroll
    for (int i = 0; i < 4; ++i) {
        int cc = c0 + ty + 8 * i, rr = r0 + tx;
        out[(size_t)cc * R + rr] = __float2bfloat16(tile[tx][ty + 8 * i]);
    }
}

// ---------- MLP weight prep: fragment-major layout ----------
// 5 units of 512x512 (W1, W2, W3, Wz half0, Wz half1). Element
// Wf[unit][wc][ks][nj][lane][j] = Wsrc[(ks*32 + (lane>>4)*8 + j)*N + o],
// o = (unit>=3)*(unit-3)*512 + wc*128 + nj*16 + (lane&15).
// A wave's step-load (wc, ks) is then 8 contiguous 1-KB chunks (nj) — coalesced.
__global__ void k_prep_mlp(const float* __restrict__ W1, const float* __restrict__ W2,
                           const float* __restrict__ W3, const float* __restrict__ Wz,
                           bf16* __restrict__ Wf)
{
    int g = blockIdx.x * 256 + threadIdx.x;   // 163840 threads
    int unit = g >> 15;
    int idx = g & 32767;
    int lane = idx & 63;
    int nj = (idx >> 6) & 7;
    int ks = (idx >> 9) & 15;
    int wc = idx >> 13;
    int lm = lane & 15, lq = lane >> 4;
    int k0 = ks * 32 + lq * 8;
    const float* src;
    int N, o;
    if (unit < 3) {
        src = (unit == 0) ? W1 : (unit == 1) ? W2 : W3;
        N = 512;
        o = wc * 128 + nj * 16 + lm;
    } else {
        src = Wz;
        N = 1024;
        o = (unit - 3) * 512 + wc * 128 + nj * 16 + lm;
    }
    VecU v;
#pragma unroll
    for (int j = 0; j < 8; ++j)
        v.s[j] = bf16_bits(src[(size_t)(k0 + j) * N + o]);
    *(uint4*)(void*)(Wf + (size_t)g * 8) = v.q;
}

// ---------- merged bf16 transposes (vectorized 64x64 tiles) ----------
// z<4: v slice of uvb[b] (t,c) -> vtb[b] (c,t); z==4: ab (k,c) -> atb (c,k)
__global__ void k_transpose5(const bf16* __restrict__ uvb, const bf16* __restrict__ ab,
                             bf16* __restrict__ vtb, bf16* __restrict__ atb)
{
    __shared__ unsigned short tile[64][65];
    const int z = blockIdx.z;
    const bf16* in;
    bf16* out;
    int in_stride, col0;
    if (z < 4) {
        in = uvb + (size_t)z * 2048 * 2048;
        out = vtb + (size_t)z * 1024 * 2048;
        in_stride = 2048;
        col0 = 1024;
    } else {
        in = ab;
        out = atb;
        in_stride = 1024;
        col0 = 0;
    }
    const int t = threadIdx.x;
    int c0 = blockIdx.x * 64, r0 = blockIdx.y * 64;
#pragma unroll
    for (int it = 0; it < 2; ++it) {
        int r = it * 32 + (t >> 3), cc = (t & 7) * 8;
        VecU v;
        v.q = *(const uint4*)(const void*)(in + (size_t)(r0 + r) * in_stride + col0 + c0 + cc);
#pragma unroll
        for (int i = 0; i < 8; ++i) tile[r][cc + i] = v.s[i];
    }
    __syncthreads();
#pragma unroll
    for (int it = 0; it < 2; ++it) {
        int c = it * 32 + (t >> 3), rr = (t & 7) * 8;
        VecU v;
#pragma unroll
        for (int i = 0; i < 8; ++i) v.s[i] = tile[rr + i][c];
        *(uint4*)(void*)(out + (size_t)(c0 + c) * 2048 + r0 + rr) = v.q;
    }
}

// ---------- gate + transpose: ud1t[b](1024 x 2048) -> ud1[b](2048 x 1024), gated by u from uv (t,c) ----------
__global__ void k_gate_transpose(const bf16* __restrict__ ud1t, const bf16* __restrict__ uv,
                                 bf16* __restrict__ out)
{
    __shared__ float tile[32][33];
    const int b = blockIdx.z;
    int c0 = blockIdx.x * 32, t0 = blockIdx.y * 32;
    int tx = threadIdx.x & 31, ty = threadIdx.x >> 5;
#pragma unroll
    for (int i = 0; i < 4; ++i) {
        int cc = c0 + ty + 8 * i;
        tile[ty + 8 * i][tx] = __bfloat162float(ud1t[((size_t)b * 1024 + cc) * 2048 + t0 + tx]);
    }
    __syncthreads();
#pragma unroll
    for (int i = 0; i < 4; ++i) {
        int t = t0 + ty + 8 * i, c = c0 + tx;
        float u = __bfloat162float(uv[((size_t)b * 2048 + t) * 2048 + c]);
        out[((size_t)b * 2048 + t) * 1024 + c] = __float2bfloat16(tile[tx][ty + 8 * i] * u);
    }
}

// ---------- x -> srms(x) as bf16 (rows of 512) ----------
__global__ void k_rms_x(const float* __restrict__ x, bf16* __restrict__ xn)
{
    int row = blockIdx.x, t = threadIdx.x;
    const float* xr = x + (size_t)row * 512;
    float a = xr[t], b = xr[t + 256];
    float v = a * a + b * b;
#pragma unroll
    for (int m = 32; m >= 1; m >>= 1) v += __shfl_xor(v, m, 64);
    __shared__ float ws[4];
    if ((t & 63) == 0) ws[t >> 6] = v;
    __syncthreads();
    float tot = ws[0] + ws[1] + ws[2] + ws[3];
    float s = 1.f / (sqrtf(tot * (1.f / 512.f)) + 1e-8f);
    bf16* o = xn + (size_t)row * 512;
    o[t] = __float2bfloat16(a * s);
    o[t + 256] = __float2bfloat16(b * s);
}

// ---------- combined kernel: blocks [0,64) = fused positional MLP, [64,1088) = uv GEMM ----------
// MLP leg v3: M=32 positions/block; weights in fragment-major layout so each
// K-step load is 8 contiguous dwordx4 per wave (no gather); depth-3 rotating
// prefetch (bufB[3][8]) to hide L2/L3 latency.
__global__ __launch_bounds__(256, 2) void k_uv_mlp(
    const bf16* __restrict__ A, const bf16* __restrict__ Bt,   // xn, Wuvt
    const float* __restrict__ bu, const float* __restrict__ bv,
    const float* __restrict__ Wp, const float* __restrict__ bp,
    const bf16* __restrict__ Wf,                                // fragment-major MLP weights
    const float* __restrict__ b1, const float* __restrict__ b2,
    const float* __restrict__ b3, const float* __restrict__ bz,
    bf16* __restrict__ uvb, bf16* __restrict__ ab)
{
    // GEMM leg LDS
    __shared__ unsigned short As[128 * 40];
    __shared__ unsigned short Bs[128 * 40];
    // MLP leg LDS
    __shared__ unsigned short X[32][520];
    __shared__ float sq[16][17];
    __shared__ float red[4][32];
    __shared__ float scale[32];

    const int tid = threadIdx.x, lane = tid & 63, w = tid >> 6;
    const int lm = lane & 15, lq = lane >> 4;

    if (blockIdx.x < 64) {
        // ================= MLP leg =================
        const int posBase = blockIdx.x * 32;

        // stage 0: X[r][:] = relu(srms(pos*Wp + bp)), two 16-row rounds
#pragma unroll
        for (int hf = 0; hf < 2; ++hf) {
            const int rl = tid >> 4;
            const int r = hf * 16 + rl;
            const int c0 = (tid & 15) * 32;
            float vals[32];
            float ssq = 0.f;
            const float fp = (float)(posBase + r);
#pragma unroll
            for (int e = 0; e < 32; ++e) {
                float z = fp * Wp[c0 + e] + bp[c0 + e];
                vals[e] = z;
                ssq += z * z;
            }
            sq[rl][tid & 15] = ssq;
            __syncthreads();
            float tot = 0.f;
#pragma unroll
            for (int i = 0; i < 16; ++i) tot += sq[rl][i];
            float s = 1.f / (sqrtf(tot * (1.f / 512.f)) + 1e-8f);
            unsigned int* xrow = (unsigned int*)&X[r][c0];
#pragma unroll
            for (int e = 0; e < 16; ++e)
                xrow[e] = packbf2(fmaxf(vals[2 * e] * s, 0.f), fmaxf(vals[2 * e + 1] * s, 0.f));
            __syncthreads();
        }

        // one 512-K GEMM pass against fragment-major unit; acc[mi][nj]
        auto layer_mm = [&](const bf16* Wu_, f32x4 (&acc)[2][8]) {
            const bf16* base = Wu_ + (size_t)w * 65536 + (size_t)lane * 8;
            bf16x8 bufB[3][8];
#pragma unroll
            for (int d = 0; d < 2; ++d)
#pragma unroll
                for (int nj = 0; nj < 8; ++nj)
                    bufB[d][nj] = *(const bf16x8*)(const void*)(base + d * 4096 + nj * 512);
#pragma unroll
            for (int ks = 0; ks < 16; ++ks) {
                const int cb = ks % 3;
                if (ks < 14) {
                    const int pf = (ks + 2) % 3;
#pragma unroll
                    for (int nj = 0; nj < 8; ++nj)
                        bufB[pf][nj] = *(const bf16x8*)(const void*)(base + (ks + 2) * 4096 + nj * 512);
                }
                bf16x8 af0 = *(const bf16x8*)(const void*)&X[lm][ks * 32 + lq * 8];
                bf16x8 af1 = *(const bf16x8*)(const void*)&X[16 + lm][ks * 32 + lq * 8];
#pragma unroll
                for (int nj = 0; nj < 8; ++nj) {
                    acc[0][nj] = __builtin_amdgcn_mfma_f32_16x16x32_bf16(af0, bufB[cb][nj], acc[0][nj], 0, 0, 0);
                    acc[1][nj] = __builtin_amdgcn_mfma_f32_16x16x32_bf16(af1, bufB[cb][nj], acc[1][nj], 0, 0, 0);
                }
            }
        };

        const float* bs[3] = {b1, b2, b3};
        for (int l = 0; l < 3; ++l) {
            f32x4 acc[2][8];
#pragma unroll
            for (int mi = 0; mi < 2; ++mi)
#pragma unroll
                for (int i = 0; i < 8; ++i) acc[mi][i] = (f32x4){0.f, 0.f, 0.f, 0.f};
            layer_mm(Wf + (size_t)l * 262144, acc);
            // bias BEFORE srms
#pragma unroll
            for (int mi = 0; mi < 2; ++mi)
#pragma unroll
                for (int nj = 0; nj < 8; ++nj) {
                    float bb = bs[l][w * 128 + nj * 16 + lm];
#pragma unroll
                    for (int r = 0; r < 4; ++r) acc[mi][nj][r] += bb;
                }
            float pr[2][4] = {{0.f, 0.f, 0.f, 0.f}, {0.f, 0.f, 0.f, 0.f}};
#pragma unroll
            for (int mi = 0; mi < 2; ++mi)
#pragma unroll
                for (int nj = 0; nj < 8; ++nj)
#pragma unroll
                    for (int r = 0; r < 4; ++r) pr[mi][r] += acc[mi][nj][r] * acc[mi][nj][r];
#pragma unroll
            for (int m = 1; m < 16; m <<= 1)
#pragma unroll
                for (int mi = 0; mi < 2; ++mi)
#pragma unroll
                    for (int r = 0; r < 4; ++r) pr[mi][r] += __shfl_xor(pr[mi][r], m);
            if (lm == 0)
#pragma unroll
                for (int mi = 0; mi < 2; ++mi)
#pragma unroll
                    for (int r = 0; r < 4; ++r) red[w][mi * 16 + lq * 4 + r] = pr[mi][r];
            __syncthreads();   // also: all waves done reading X for this layer
            if (tid < 32) {
                float tot = red[0][tid] + red[1][tid] + red[2][tid] + red[3][tid];
                scale[tid] = 1.f / (sqrtf(tot * (1.f / 512.f)) + 1e-8f);
            }
            __syncthreads();
#pragma unroll
            for (int mi = 0; mi < 2; ++mi)
#pragma unroll
                for (int nj = 0; nj < 8; ++nj) {
                    int col = w * 128 + nj * 16 + lm;
#pragma unroll
                    for (int r = 0; r < 4; ++r) {
                        int row = mi * 16 + lq * 4 + r;
                        float z = fmaxf(acc[mi][nj][r] * scale[row], 0.f);
                        *(unsigned short*)&X[row][col] = bf16_bits(z);
                    }
                }
            __syncthreads();
        }

        // final layer: Wz as two fragment-major 512-col units; +bz, *gamma^pos
#pragma unroll
        for (int h = 0; h < 2; ++h) {
            f32x4 acc[2][8];
#pragma unroll
            for (int mi = 0; mi < 2; ++mi)
#pragma unroll
                for (int i = 0; i < 8; ++i) acc[mi][i] = (f32x4){0.f, 0.f, 0.f, 0.f};
            layer_mm(Wf + (size_t)(3 + h) * 262144, acc);
#pragma unroll
            for (int mi = 0; mi < 2; ++mi)
#pragma unroll
                for (int nj = 0; nj < 8; ++nj) {
                    int col = h * 512 + w * 128 + nj * 16 + lm;
                    float bb = bz[col];
#pragma unroll
                    for (int r = 0; r < 4; ++r) {
                        int pos = posBase + mi * 16 + lq * 4 + r;
                        float z = (acc[mi][nj][r] + bb) * exp2f((float)pos * GAMMA_LOG2);
                        ab[(size_t)pos * 1024 + col] = __float2bfloat16(z);
                    }
                }
        }
        return;
    }

    // ================= GEMM leg: uv = silu(xn @ Wuvt + [bu|bv]) =================
    const int gid = (int)blockIdx.x - 64;
    const int wm = (w >> 1) * 64, wn = (w & 1) * 64;
    const long rowBase = (long)(gid & 63) * 128, colBase = (long)(gid >> 6) * 128;

    f32x4 acc[4][4];
    f32x4 zz = {0.f, 0.f, 0.f, 0.f};
#pragma unroll
    for (int i = 0; i < 4; ++i)
#pragma unroll
        for (int j = 0; j < 4; ++j) acc[i][j] = zz;

    for (int k0 = 0; k0 < 512; k0 += 32) {
#pragma unroll
        for (int i = 0; i < 2; ++i) {
            int idx = (i * 256 + tid) * 8;
            int r = idx >> 5, kk = idx & 31;
            *(uint4*)(void*)(As + r * 40 + kk) =
                *(const uint4*)(const void*)(A + (rowBase + r) * 512 + k0 + kk);
        }
#pragma unroll
        for (int i = 0; i < 2; ++i) {
            int idx = (i * 256 + tid) * 8;
            int r = idx >> 5, kk = idx & 31;
            *(uint4*)(void*)(Bs + r * 40 + kk) =
                *(const uint4*)(const void*)(Bt + (colBase + r) * 512 + k0 + kk);
        }
        __syncthreads();
        bf16x8 af[4], bfr[4];
#pragma unroll
        for (int mi = 0; mi < 4; ++mi)
            af[mi] = *(const bf16x8*)(const void*)(As + (wm + mi * 16 + lm) * 40 + lq * 8);
#pragma unroll
        for (int nj = 0; nj < 4; ++nj)
            bfr[nj] = *(const bf16x8*)(const void*)(Bs + (wn + nj * 16 + lm) * 40 + lq * 8);
#pragma unroll
        for (int mi = 0; mi < 4; ++mi)
#pragma unroll
            for (int nj = 0; nj < 4; ++nj)
                acc[mi][nj] = __builtin_amdgcn_mfma_f32_16x16x32_bf16(af[mi], bfr[nj], acc[mi][nj], 0, 0, 0);
        __syncthreads();
    }

#pragma unroll
    for (int mi = 0; mi < 4; ++mi)
#pragma unroll
        for (int nj = 0; nj < 4; ++nj) {
            long col = colBase + wn + nj * 16 + lm;
            float bb = (col < 1024) ? bu[col] : bv[col - 1024];
#pragma unroll
            for (int r = 0; r < 4; ++r) {
                long row = rowBase + wm + mi * 16 + lq * 4 + r;
                float z = acc[mi][nj][r] + bb;
                z = z / (1.f + __expf(-z));
                uvb[(size_t)row * 2048 + col] = __float2bfloat16(z);
            }
        }
}

// ---------- MFMA bf16 GEMM (out projection) ----------
template <int BM, int BN, int WM, int WN>
__global__ __launch_bounds__(256, 2) void k_gemm_out(
    const bf16* __restrict__ A, const bf16* __restrict__ Bt,
    const float* __restrict__ bias0, const float* __restrict__ addsrc,
    float* __restrict__ outp, int M, int N, int K)
{
    constexpr int BK = 32, LDT = BK + 8;
    constexpr int MI = WM / 16, NJ = WN / 16;
    constexpr int WCOLS = BN / WN;
    __shared__ unsigned short As[BM * LDT];
    __shared__ unsigned short Bs[BN * LDT];
    const int tid = threadIdx.x;
    const int lane = tid & 63, w = tid >> 6;
    const int wm = (w / WCOLS) * WM, wn = (w % WCOLS) * WN;
    const int lm = lane & 15, lq = lane >> 4;
    const long rowBase = (long)blockIdx.x * BM, colBase = (long)blockIdx.y * BN;

    f32x4 acc[MI][NJ];
    f32x4 zz = {0.f, 0.f, 0.f, 0.f};
#pragma unroll
    for (int i = 0; i < MI; ++i)
#pragma unroll
        for (int j = 0; j < NJ; ++j) acc[i][j] = zz;

    for (int k0 = 0; k0 < K; k0 += BK) {
#pragma unroll
        for (int i = 0; i < BM / 64; ++i) {
            int idx = (i * 256 + tid) * 8;
            int r = idx >> 5, kk = idx & 31;
            *(uint4*)(void*)(As + r * LDT + kk) =
                *(const uint4*)(const void*)(A + (rowBase + r) * K + k0 + kk);
        }
#pragma unroll
        for (int i = 0; i < BN / 64; ++i) {
            int idx = (i * 256 + tid) * 8;
            int r = idx >> 5, kk = idx & 31;
            *(uint4*)(void*)(Bs + r * LDT + kk) =
                *(const uint4*)(const void*)(Bt + (colBase + r) * K + k0 + kk);
        }
        __syncthreads();
        bf16x8 af[MI], bfr[NJ];
#pragma unroll
        for (int mi = 0; mi < MI; ++mi)
            af[mi] = *(const bf16x8*)(const void*)(As + (wm + mi * 16 + lm) * LDT + lq * 8);
#pragma unroll
        for (int nj = 0; nj < NJ; ++nj)
            bfr[nj] = *(const bf16x8*)(const void*)(Bs + (wn + nj * 16 + lm) * LDT + lq * 8);
#pragma unroll
        for (int mi = 0; mi < MI; ++mi)
#pragma unroll
            for (int nj = 0; nj < NJ; ++nj)
                acc[mi][nj] = __builtin_amdgcn_mfma_f32_16x16x32_bf16(af[mi], bfr[nj], acc[mi][nj], 0, 0, 0);
        __syncthreads();
    }

#pragma unroll
    for (int mi = 0; mi < MI; ++mi)
#pragma unroll
        for (int nj = 0; nj < NJ; ++nj) {
            long col = colBase + wn + nj * 16 + lm;
#pragma unroll
            for (int r = 0; r < 4; ++r) {
                long row = rowBase + wm + mi * 16 + lq * 4 + r;
                size_t off = (size_t)row * N + col;
                outp[off] = acc[mi][nj][r] + bias0[col] + addsrc[off];
            }
        }
}

// ---------- Toeplitz-MFMA depthwise causal conv ----------
__global__ __launch_bounds__(256, 4) void k_conv_mfma(
    const bf16* __restrict__ vt, const bf16* __restrict__ at, bf16* __restrict__ ud1t)
{
    __shared__ unsigned short ash2[2][2068];  // reversed filter, 2 shifted copies
    __shared__ unsigned short vsh[4][3072];   // per-batch v, stride 24 per 16-elem tile

    const int tid = threadIdx.x, lane = tid & 63, w = tid >> 6;
    const int c = blockIdx.x;

    {
        const unsigned short* asrc = (const unsigned short*)(at + (size_t)c * 2048);
        for (int i = tid; i < 2068; i += 256) {
#pragma unroll
            for (int k = 0; k < 2; ++k) {
                int src = 2047 - i - k;
                ash2[k][i] = (src >= 0) ? asrc[src] : (unsigned short)0;
            }
        }
    }
    {
        const bf16* vsrc = vt + ((size_t)w * 1024 + c) * 2048;
#pragma unroll
        for (int q = 0; q < 4; ++q) {
            int li = q * 64 + lane;
            int tile = li >> 1, hf = li & 1;
            *(uint4*)(void*)&vsh[w][tile * 24 + hf * 8] =
                *(const uint4*)(const void*)(vsrc + li * 8);
        }
    }
    __syncthreads();

    const int lm = lane & 15, lq = lane >> 4;
    const int h = lq >> 1, p0 = (lq & 1) * 8;
    const int kcopy = (lm + 1) & 1;
    const int base = 31 - 16 * h - lm + p0 - kcopy;
    const unsigned int* aw = (const unsigned int*)(void*)&ash2[kcopy][0] + (base >> 1);
    const unsigned short* vw = &vsh[w][0];

    f32x4 acc[8];
    f32x4 zz = {0.f, 0.f, 0.f, 0.f};
#pragma unroll
    for (int i = 0; i < 8; ++i) acc[i] = zz;
    const bf16x8 zfrag = (bf16x8)(short)0;

    for (int dt = 0; dt < 8; ++dt) {
#pragma unroll
        for (int d2 = 0; d2 < 16; d2 += 2) {
            const int dd = dt * 16 + d2;
            const int m16 = (63 - (dd >> 1)) * 16;
            union { unsigned int u[4]; bf16x8 v; } af;
            af.u[0] = aw[m16 + 0];
            af.u[1] = aw[m16 + 1];
            af.u[2] = aw[m16 + 2];
            af.u[3] = aw[m16 + 3];
            const int tb = lm - dd - h;
            for (int jg = dt; jg < 8; ++jg) {
                int tile = jg * 16 + tb;
                int T = tile > 0 ? tile : 0;
                bf16x8 vf = *(const bf16x8*)(const void*)(vw + T * 24 + p0);
                if (tile < 0) vf = zfrag;
                acc[jg] = __builtin_amdgcn_mfma_f32_16x16x32_bf16(af.v, vf, acc[jg], 0, 0, 0);
            }
        }
    }

    __syncthreads();
    float* stg = (float*)(void*)((char*)(void*)&ash2[0][0] + w * 1024);
    bf16* dst = ud1t + ((size_t)w * 1024 + c) * 2048;
#pragma unroll
    for (int jg = 0; jg < 8; ++jg) {
        *(f32x4*)(void*)&stg[lm * 16 + lq * 4] = acc[jg];
        f32x4 vv = *(const f32x4*)(const void*)&stg[lane * 4];
        uint2 o;
        o.x = packbf2(vv.x, vv.y);
        o.y = packbf2(vv.z, vv.w);
        *(uint2*)(void*)(dst + jg * 256 + lane * 4) = o;
    }
}

extern "C" void kernel_launch(void* const* d_in, const int* in_sizes, int n_in,
                              void* d_out, int out_size, void* d_ws, size_t ws_size,
                              hipStream_t stream)
{
    const float* x  = (const float*)d_in[0];
    const float* Wu = (const float*)d_in[1];
    const float* bu = (const float*)d_in[2];
    const float* Wv = (const float*)d_in[3];
    const float* bv = (const float*)d_in[4];
    const float* Wo = (const float*)d_in[5];
    const float* bo = (const float*)d_in[6];
    const float* Wp = (const float*)d_in[7];
    const float* bp = (const float*)d_in[8];
    const float* W1 = (const float*)d_in[9];
    const float* b1 = (const float*)d_in[10];
    const float* W2 = (const float*)d_in[11];
    const float* b2 = (const float*)d_in[12];
    const float* W3 = (const float*)d_in[13];
    const float* b3 = (const float*)d_in[14];
    const float* Wz = (const float*)d_in[15];
    const float* bz = (const float*)d_in[16];

    char* p = (char*)d_ws;
    auto carve = [&](size_t bytes) { void* q = (void*)p; p += (bytes + 255) & ~(size_t)255; return q; };
    bf16*  xn   = (bf16*)carve((size_t)8192 * 512 * 2);
    bf16*  Wuvt = (bf16*)carve((size_t)2048 * 512 * 2);
    bf16*  Wot  = (bf16*)carve((size_t)512 * 1024 * 2);
    bf16*  Wf   = (bf16*)carve((size_t)5 * 262144 * 2);       // fragment-major MLP weights
    bf16*  uvb  = (bf16*)carve((size_t)8192 * 2048 * 2);      // [u | v] silu outputs (t, c)
    bf16*  ud1  = (bf16*)carve((size_t)8192 * 1024 * 2);      // u * conv, (t, c)
    bf16*  ab   = (bf16*)carve((size_t)2048 * 1024 * 2);      // decayed filter a[k,c]
    bf16*  vtb  = (bf16*)carve((size_t)4 * 1024 * 2048 * 2);  // v (b,c,t)
    bf16*  atb  = (bf16*)carve((size_t)1024 * 2048 * 2);      // a (c,k)
    bf16*  ud1t = (bf16*)carve((size_t)4 * 1024 * 2048 * 2);  // conv result (b,c,t)

    // weight prep: 3 transposes (Wu, Wv, Wo)
    PrepArgs pa;
    const float* srcs[3] = {Wu, Wv, Wo};
    bf16* dsts[3] = {Wuvt, Wuvt + (size_t)1024 * 512, Wot};
    int Rs[3] = {512, 512, 1024};
    int Cs[3] = {1024, 1024, 512};
    int acc_t = 0;
    for (int i = 0; i < 3; ++i) {
        pa.src[i] = srcs[i]; pa.dst[i] = dsts[i]; pa.R[i] = Rs[i]; pa.C[i] = Cs[i];
        pa.pfx[i] = acc_t;
        acc_t += (Rs[i] / 32) * (Cs[i] / 32);
    }
    pa.pfx[3] = acc_t;  // 1536
    k_prep<<<acc_t, 256, 0, stream>>>(pa);

    // MLP weights -> fragment-major layout
    k_prep_mlp<<<640, 256, 0, stream>>>(W1, W2, W3, Wz, Wf);

    k_rms_x<<<8192, 256, 0, stream>>>(x, xn);

    // combined: uv GEMM + fused positional MLP (MLP blocks first)
    k_uv_mlp<<<1088, 256, 0, stream>>>(xn, Wuvt, bu, bv, Wp, bp,
                                       Wf, b1, b2, b3, bz, uvb, ab);

    // v -> (b,c,t) and a -> (c,k) in one launch (vectorized 64x64 tiles)
    k_transpose5<<<dim3(16, 32, 5), 256, 0, stream>>>(uvb, ab, vtb, atb);

    // causal depthwise conv via Toeplitz-MFMA (block = channel x 4 batches)
    k_conv_mfma<<<dim3(1024), 256, 0, stream>>>(vtb, atb, ud1t);

    // gate by u and transpose back to (t, c)
    k_gate_transpose<<<dim3(32, 64, 4), 256, 0, stream>>>(ud1t, uvb, ud1);

    // y = ud1 @ Wo + bo + x
    k_gemm_out<128, 128, 64, 64><<<dim3(64, 4), 256, 0, stream>>>(
        ud1, Wot, bo, x, (float*)d_out, 8192, 512, 1024);
}